// Round 5
// baseline (699.869 us; speedup 1.0000x reference)
//
#include <hip/hip_runtime.h>
#include <stdint.h>

#define SEQ 1024
#define NB  1024
#define HD  64
#define BH  (NB*HD)            // elements per timestep plane
#define RPW 16                 // batch rows per wave (= per block)

typedef _Float16 f16x8 __attribute__((ext_vector_type(8)));
typedef float    f32x4 __attribute__((ext_vector_type(4)));
typedef uint32_t u32x4 __attribute__((ext_vector_type(4)));

#define L2E2 2.8853900817779268f   // 2*log2(e), folded into weights/bias

__device__ __forceinline__ uint32_t pkrtz(float a, float b) {
    auto h = __builtin_amdgcn_cvt_pkrtz(a, b);   // a->lo, b->hi
    return __builtin_bit_cast(uint32_t, h);
}
// tanh from prescaled z = 2*log2e*x:  tanh|x| = 2r-1, r = 1/(1+exp2(-|z|)).
// a = 1+e is in (1,2] -> linear seed + 2 Newton for r (no v_rcp, full-rate VALU).
__device__ __forceinline__ float tanh_ps(float z) {
    float e = __builtin_amdgcn_exp2f(-__builtin_fabsf(z));  // -|z| folds to modifier
    float a = e + 1.0f;
    float r = __builtin_fmaf(-0.5f, a, 1.45711f);           // seed, rel err ~6e-2
    r = r * __builtin_fmaf(-a, r, 2.0f);                    // Newton 1 -> ~4e-3
    r = r * __builtin_fmaf(-a, r, 2.0f);                    // Newton 2 -> ~2e-5
    float m = __builtin_fmaf(2.0f, r, -1.0f);               // tanh|x| in [0,1)
    return __builtin_copysignf(m, z);
}

__global__ __launch_bounds__(64, 1) void rnn_kernel(
    const float* __restrict__ x,  const float* __restrict__ h0,
    const float* __restrict__ Wx, const float* __restrict__ bx,
    const float* __restrict__ Wh, const float* __restrict__ bh,
    float* __restrict__ out)
{
    const int lane = threadIdx.x;          // single wave per block
    const int g    = lane >> 4;            // 16-lane group 0..3
    const int n    = lane & 15;            // MFMA col = batch row (all 16 valid)
    const int R0   = blockIdx.x * RPW;
    const size_t rowoff = (size_t)(R0 + n) * HD;

    // ---- K-permuted, prescaled weights ----
    // frag[m][T] elem e (HW k=8g+e) = W[16m+n][ 16*(e>>1) + 4g + 2T + (e&1) ] * L2E2.
    // This permutation makes the C-layout tanh pairs directly usable as B-frags.
    f16x8 whA[4][2], wxA[4][2];
    #pragma unroll
    for (int m = 0; m < 4; ++m) {
        #pragma unroll
        for (int T = 0; T < 2; ++T) {
            u32x4 dw, dx;
            #pragma unroll
            for (int q = 0; q < 4; ++q) {
                const int c = 16*q + 4*g + 2*T;
                const float* wp = Wh + (size_t)(16*m + n) * HD + c;
                const float* xq = Wx + (size_t)(16*m + n) * HD + c;
                dw[q] = pkrtz(wp[0]*L2E2, wp[1]*L2E2);
                dx[q] = pkrtz(xq[0]*L2E2, xq[1]*L2E2);
            }
            whA[m][T] = __builtin_bit_cast(f16x8, dw);
            wxA[m][T] = __builtin_bit_cast(f16x8, dx);
        }
    }
    // combined bias (prescaled), C-layout: reg r <-> ch 16m+4g+r
    f32x4 biasf[4];
    #pragma unroll
    for (int m = 0; m < 4; ++m) {
        f32x4 b1 = *(const f32x4*)(bh + 16*m + 4*g);
        f32x4 b2 = *(const f32x4*)(bx + 16*m + 4*g);
        biasf[m] = (b1 + b2) * L2E2;
    }

    // ---- initial h frags (permuted layout): fragT.dword[q] = h0[row][16q+4g+2T..+1] ----
    f16x8 fh0, fh1;
    {
        u32x4 c0, c1;
        #pragma unroll
        for (int q = 0; q < 4; ++q) {
            f32x4 v = *(const f32x4*)(h0 + rowoff + 16*q + 4*g);
            c0[q] = pkrtz(v[0], v[1]);
            c1[q] = pkrtz(v[2], v[3]);
        }
        fh0 = __builtin_bit_cast(f16x8, c0);
        fh1 = __builtin_bit_cast(f16x8, c1);
    }

    // ---- xp(0) = Wx*x(0) + bias (prescaled) ----
    f32x4 xp[4];
    {
        u32x4 c0, c1;
        #pragma unroll
        for (int q = 0; q < 4; ++q) {
            f32x4 v = *(const f32x4*)(x + rowoff + 16*q + 4*g);
            c0[q] = pkrtz(v[0], v[1]);
            c1[q] = pkrtz(v[2], v[3]);
        }
        f16x8 fx0 = __builtin_bit_cast(f16x8, c0);
        f16x8 fx1 = __builtin_bit_cast(f16x8, c1);
        #pragma unroll
        for (int m = 0; m < 4; ++m) {
            f32x4 tq = __builtin_amdgcn_mfma_f32_16x16x32_f16(wxA[m][0], fx0, biasf[m], 0, 0, 0);
            xp[m]    = __builtin_amdgcn_mfma_f32_16x16x32_f16(wxA[m][1], fx1, tq,       0, 0, 0);
        }
    }

    // ---- x register ring (depth 4): slot s holds x(t) as 4 f32x4; preload 1..3 ----
    f32x4 ring[4][4];
    #pragma unroll
    for (int s = 1; s <= 3; ++s) {
        const float* xs = x + (size_t)s * BH + rowoff;
        #pragma unroll
        for (int q = 0; q < 4; ++q) ring[s][q] = *(const f32x4*)(xs + 16*q + 4*g);
    }

    for (int tb = 0; tb < SEQ; tb += 4) {
        #pragma unroll
        for (int u = 0; u < 4; ++u) {
            const int t = tb + u;

            // refill slot u with x(t+4) (fire & forget; consumed 3 steps later)
            {
                int tl = t + 4; tl = tl > SEQ - 1 ? SEQ - 1 : tl;
                const float* xs = x + (size_t)tl * BH + rowoff;
                #pragma unroll
                for (int q = 0; q < 4; ++q) ring[u][q] = *(const f32x4*)(xs + 16*q + 4*g);
            }

            // critical chain: acc = Wh*h(t) + xp(t)
            f32x4 acc[4];
            #pragma unroll
            for (int m = 0; m < 4; ++m) {
                f32x4 hp = __builtin_amdgcn_mfma_f32_16x16x32_f16(whA[m][0], fh0, xp[m], 0, 0, 0);
                acc[m]   = __builtin_amdgcn_mfma_f32_16x16x32_f16(whA[m][1], fh1, hp,    0, 0, 0);
            }

            // off-chain: xp(t+1) from ring slot (u+1)&3
            if (t + 1 < SEQ) {
                const int sc = (u + 1) & 3;
                u32x4 c0, c1;
                #pragma unroll
                for (int q = 0; q < 4; ++q) {
                    f32x4 v = ring[sc][q];
                    c0[q] = pkrtz(v[0], v[1]);
                    c1[q] = pkrtz(v[2], v[3]);
                }
                f16x8 fx0 = __builtin_bit_cast(f16x8, c0);
                f16x8 fx1 = __builtin_bit_cast(f16x8, c1);
                #pragma unroll
                for (int m = 0; m < 4; ++m) {
                    f32x4 tq = __builtin_amdgcn_mfma_f32_16x16x32_f16(wxA[m][0], fx0, biasf[m], 0, 0, 0);
                    xp[m]    = __builtin_amdgcn_mfma_f32_16x16x32_f16(wxA[m][1], fx1, tq,       0, 0, 0);
                }
            }

            // tanh; pkrtz pairs ARE the next-step B-frag dwords (K-permute payoff)
            f32x4 tv[4];
            u32x4 c0, c1;
            #pragma unroll
            for (int m = 0; m < 4; ++m) {
                #pragma unroll
                for (int r = 0; r < 4; ++r) tv[m][r] = tanh_ps(acc[m][r]);
                c0[m] = pkrtz(tv[m][0], tv[m][1]);
                c1[m] = pkrtz(tv[m][2], tv[m][3]);
            }
            fh0 = __builtin_bit_cast(f16x8, c0);
            fh1 = __builtin_bit_cast(f16x8, c1);

            // off-chain stores (C-layout is contiguous f32x4 per tile)
            {
                float* dst = out + (size_t)t * BH + rowoff + 4*g;
                #pragma unroll
                for (int m = 0; m < 4; ++m) *(f32x4*)(dst + 16*m) = tv[m];
                if (t == SEQ - 1) {
                    float* dl = out + (size_t)SEQ * BH + rowoff + 4*g;
                    #pragma unroll
                    for (int m = 0; m < 4; ++m) *(f32x4*)(dl + 16*m) = tv[m];
                }
            }
        }
    }
}

extern "C" void kernel_launch(void* const* d_in, const int* in_sizes, int n_in,
                              void* d_out, int out_size, void* d_ws, size_t ws_size,
                              hipStream_t stream) {
    const float* x  = (const float*)d_in[0];
    const float* h  = (const float*)d_in[1];
    const float* Wx = (const float*)d_in[2];
    const float* bx = (const float*)d_in[3];
    const float* Wh = (const float*)d_in[4];
    const float* bh = (const float*)d_in[5];
    float* out = (float*)d_out;

    rnn_kernel<<<dim3(NB / RPW), dim3(64), 0, stream>>>(x, h, Wx, bx, Wh, bh, out);
}

// Round 6
// 310.019 us; speedup vs baseline: 2.2575x; 2.2575x over previous
//
#include <hip/hip_runtime.h>
#include <stdint.h>

#define SEQ 1024
#define NB  1024
#define HD  64
#define BH  (NB*HD)            // elements per timestep plane
#define RPB 16                 // batch rows per block

typedef _Float16 f16x8 __attribute__((ext_vector_type(8)));
typedef float    f32x4 __attribute__((ext_vector_type(4)));
typedef uint32_t u32x4 __attribute__((ext_vector_type(4)));

#define L2E2 2.8853900817779268f   // 2*log2(e), folded into weights/bias

__device__ __forceinline__ uint32_t pkrtz(float a, float b) {
    auto h = __builtin_amdgcn_cvt_pkrtz(a, b);   // a->lo, b->hi
    return __builtin_bit_cast(uint32_t, h);
}
// tanh from prescaled z = 2*log2e*x: tanh|x| = 2r-1, r = 1/(1+exp2(-|z|)).
// a = 1+e in (1,2] -> linear seed + 2 Newton (full-rate FMA, no v_rcp).
__device__ __forceinline__ float tanh_ps(float z) {
    float e = __builtin_amdgcn_exp2f(-__builtin_fabsf(z));
    float a = e + 1.0f;
    float r = __builtin_fmaf(-0.5f, a, 1.45711f);
    r = r * __builtin_fmaf(-a, r, 2.0f);
    r = r * __builtin_fmaf(-a, r, 2.0f);
    float m = __builtin_fmaf(2.0f, r, -1.0f);
    return __builtin_copysignf(m, z);
}
// Barrier draining ONLY lgkmcnt: global loads/stores stay in flight.
__device__ __forceinline__ void sync_lds() {
    asm volatile("s_waitcnt lgkmcnt(0)" ::: "memory");
    __builtin_amdgcn_s_barrier();
    asm volatile("" ::: "memory");
}

__global__ __launch_bounds__(256, 1) void rnn_kernel(
    const float* __restrict__ x,  const float* __restrict__ h0,
    const float* __restrict__ Wx, const float* __restrict__ bx,
    const float* __restrict__ Wh, const float* __restrict__ bh,
    float* __restrict__ out)
{
    // frag dword pools: [buf][T][producing wave q][lane]  (all conflict-free)
    __shared__ uint32_t hw[2][2][4][64];
    __shared__ uint32_t xw[2][2][4][64];

    const int tid  = threadIdx.x;
    const int w    = tid >> 6;         // wave: owns output channels [16w,16w+16)
    const int lane = tid & 63;
    const int g    = lane >> 4;        // 16-lane group
    const int n    = lane & 15;        // MFMA col = batch row (all 16 valid)
    const int R0   = blockIdx.x * RPB;
    const size_t row = (size_t)(R0 + n) * HD;
    const size_t xsoff = row + 16 * w + 4 * g;   // this thread's staging slice

    // ---- K-permuted prescaled weights for this wave's 16 channels ----
    // A-frag[T] elem e (k=8g+e) = W[16w+n][ c(T,e)=16(e>>1)+4g+2T+(e&1) ] * L2E2
    f16x8 whA[2], wxA[2];
    #pragma unroll
    for (int T = 0; T < 2; ++T) {
        u32x4 dw, dx;
        #pragma unroll
        for (int q = 0; q < 4; ++q) {
            const int c = 16*q + 4*g + 2*T;
            const float* wp = Wh + (size_t)(16*w + n) * HD + c;
            const float* xr = Wx + (size_t)(16*w + n) * HD + c;
            dw[q] = pkrtz(wp[0]*L2E2, wp[1]*L2E2);
            dx[q] = pkrtz(xr[0]*L2E2, xr[1]*L2E2);
        }
        whA[T] = __builtin_bit_cast(f16x8, dw);
        wxA[T] = __builtin_bit_cast(f16x8, dx);
    }
    f32x4 biasf;
    {
        f32x4 b1 = *(const f32x4*)(bh + 16*w + 4*g);
        f32x4 b2 = *(const f32x4*)(bx + 16*w + 4*g);
        biasf = (b1 + b2) * L2E2;
    }

    // ---- stage h(0) and x(2) into buf 0 (thread (w,g,n) -> slot [T][w][lane]) ----
    {
        f32x4 hv = *(const f32x4*)(h0 + xsoff);
        hw[0][0][w][lane] = pkrtz(hv[0], hv[1]);
        hw[0][1][w][lane] = pkrtz(hv[2], hv[3]);
        f32x4 xv = *(const f32x4*)(x + (size_t)2 * BH + xsoff);
        xw[0][0][w][lane] = pkrtz(xv[0], xv[1]);
        xw[0][1][w][lane] = pkrtz(xv[2], xv[3]);
    }

    // ---- xp(0), xp(1) via per-lane gathered frags (prologue only) ----
    f32x4 xp0, xp1;
    #pragma unroll
    for (int s = 0; s < 2; ++s) {
        u32x4 c0, c1;
        #pragma unroll
        for (int q = 0; q < 4; ++q) {
            f32x4 v = *(const f32x4*)(x + (size_t)s * BH + row + 16*q + 4*g);
            c0[q] = pkrtz(v[0], v[1]);
            c1[q] = pkrtz(v[2], v[3]);
        }
        f16x8 f0 = __builtin_bit_cast(f16x8, c0);
        f16x8 f1 = __builtin_bit_cast(f16x8, c1);
        f32x4 tq = __builtin_amdgcn_mfma_f32_16x16x32_f16(wxA[0], f0, biasf, 0, 0, 0);
        f32x4 rv = __builtin_amdgcn_mfma_f32_16x16x32_f16(wxA[1], f1, tq,    0, 0, 0);
        if (s == 0) xp0 = rv; else xp1 = rv;
    }

    // ---- reg ring: at step t stage x(t+3) from slot (u+3)&3, refill x(t+7) ----
    f32x4 ring[4];
    ring[3] = *(const f32x4*)(x + (size_t)3 * BH + xsoff);
    ring[0] = *(const f32x4*)(x + (size_t)4 * BH + xsoff);
    ring[1] = *(const f32x4*)(x + (size_t)5 * BH + xsoff);
    ring[2] = *(const f32x4*)(x + (size_t)6 * BH + xsoff);

    const f32x4 zf = {0.f, 0.f, 0.f, 0.f};
    float* optr = out + xsoff;

    sync_lds();

    for (int tb = 0; tb < SEQ; tb += 4) {
        #pragma unroll
        for (int u = 0; u < 4; ++u) {
            const int t = tb + u;
            const int P = u & 1;          // == t&1 (tb % 4 == 0)
            const int Q = (u + 1) & 1;

            // frag reads (fh for t, fx for t+2) — issued up front, pipelined
            u32x4 hc0, hc1, xc0, xc1;
            #pragma unroll
            for (int q = 0; q < 4; ++q) {
                hc0[q] = hw[P][0][q][lane];
                hc1[q] = hw[P][1][q][lane];
                xc0[q] = xw[P][0][q][lane];
                xc1[q] = xw[P][1][q][lane];
            }
            f16x8 fh0 = __builtin_bit_cast(f16x8, hc0);
            f16x8 fh1 = __builtin_bit_cast(f16x8, hc1);
            f16x8 fx0 = __builtin_bit_cast(f16x8, xc0);
            f16x8 fx1 = __builtin_bit_cast(f16x8, xc1);

            // critical chain: two PARALLEL Wh MFMAs (+ xp as C-input)
            f32x4 xpu = (u & 1) ? xp1 : xp0;
            f32x4 pA = __builtin_amdgcn_mfma_f32_16x16x32_f16(whA[0], fh0, xpu, 0, 0, 0);
            f32x4 pB = __builtin_amdgcn_mfma_f32_16x16x32_f16(whA[1], fh1, zf,  0, 0, 0);

            // off-chain: xp(t+2) (fills acc latency on the matrix pipe)
            {
                f32x4 tq = __builtin_amdgcn_mfma_f32_16x16x32_f16(wxA[0], fx0, biasf, 0, 0, 0);
                f32x4 rv = __builtin_amdgcn_mfma_f32_16x16x32_f16(wxA[1], fx1, tq,    0, 0, 0);
                if (u & 1) xp1 = rv; else xp0 = rv;
            }

            f32x4 acc = pA + pB;
            f32x4 tv;
            #pragma unroll
            for (int r = 0; r < 4; ++r) tv[r] = tanh_ps(acc[r]);

            // h(t+1) pairs ARE the B-frag dwords (K-permute): 2 conflict-free writes
            hw[Q][0][w][lane] = pkrtz(tv[0], tv[1]);
            hw[Q][1][w][lane] = pkrtz(tv[2], tv[3]);

            // stage x(t+3) frags; refill ring with x(t+7) (fire & forget)
            {
                f32x4 v = ring[(u + 3) & 3];
                xw[Q][0][w][lane] = pkrtz(v[0], v[1]);
                xw[Q][1][w][lane] = pkrtz(v[2], v[3]);
                int tl = t + 7; tl = tl > SEQ - 1 ? SEQ - 1 : tl;
                ring[(u + 3) & 3] = *(const f32x4*)(x + (size_t)tl * BH + xsoff);
            }

            // off-chain store (vmcnt never drained)
            *(f32x4*)optr = tv;
            if (t == SEQ - 1) *(f32x4*)(optr + BH) = tv;   // h_last plane
            optr += BH;

            sync_lds();
        }
    }
}

extern "C" void kernel_launch(void* const* d_in, const int* in_sizes, int n_in,
                              void* d_out, int out_size, void* d_ws, size_t ws_size,
                              hipStream_t stream) {
    const float* x  = (const float*)d_in[0];
    const float* h  = (const float*)d_in[1];
    const float* Wx = (const float*)d_in[2];
    const float* bx = (const float*)d_in[3];
    const float* Wh = (const float*)d_in[4];
    const float* bh = (const float*)d_in[5];
    float* out = (float*)d_out;

    rnn_kernel<<<dim3(NB / RPB), dim3(256), 0, stream>>>(x, h, Wx, bx, Wh, bh, out);
}